// Round 1
// baseline (226.013 us; speedup 1.0000x reference)
//
#include <hip/hip_runtime.h>

// CRF forward logZ. Inputs (setup_inputs order):
//   d_in[0] words  int32 [2048][256]
//   d_in[1] ThetaB f32   [64][128]
//   d_in[2] WA     f32   [64][64]
//   d_in[3] E      f32   [50002][128]
// out: f32 [2048] logZ
// ws: Bt table [50002][64] f32 = 12.8 MB

#define VOCAB   50000
#define NROWS   50002   // V + 2
#define DDIM    128
#define KTAGS   64
#define EOS_T   62
#define BOS_T   63
#define BATCH   2048
#define TLEN    256
#define TINYV   1e-45f

// ---------------------------------------------------------------------------
// Kernel 1: Bt[w][k] = exp(sum_d ThetaB[k][d] * E[w][d]); rows k>=62 -> TINY.
// thread = word, 32 tags per thread (tag-half per block). ThetaB addresses are
// block-uniform -> scalar loads; E is per-lane sequential float4 (L1-friendly).
// ---------------------------------------------------------------------------
__global__ __launch_bounds__(256) void emis_table_kernel(
    const float* __restrict__ ThetaB, const float* __restrict__ E,
    float* __restrict__ Bt)
{
    const int wblock = blockIdx.x >> 1;
    const int khalf  = blockIdx.x & 1;           // 0: tags 0..31, 1: tags 32..63
    const int w = wblock * 256 + threadIdx.x;
    if (w >= NROWS) return;

    const float4* E4 = (const float4*)E;         // row = 32 float4
    const float4* T4 = (const float4*)ThetaB;    // row = 32 float4

    float acc[32];
#pragma unroll
    for (int kk = 0; kk < 32; ++kk) acc[kk] = 0.f;

    for (int d4 = 0; d4 < 32; ++d4) {
        float4 e = E4[w * 32 + d4];
#pragma unroll
        for (int kk = 0; kk < 32; ++kk) {
            float4 tb = T4[(khalf * 32 + kk) * 32 + d4];   // block-uniform -> s_load
            acc[kk] = fmaf(e.x, tb.x, acc[kk]);
            acc[kk] = fmaf(e.y, tb.y, acc[kk]);
            acc[kk] = fmaf(e.z, tb.z, acc[kk]);
            acc[kk] = fmaf(e.w, tb.w, acc[kk]);
        }
    }

    float outv[32];
#pragma unroll
    for (int kk = 0; kk < 32; ++kk) outv[kk] = expf(acc[kk]);
    if (khalf) { outv[30] = TINYV; outv[31] = TINYV; }   // tags 62, 63

    float4* dst = (float4*)(Bt + (size_t)w * KTAGS + khalf * 32);
#pragma unroll
    for (int q = 0; q < 8; ++q)
        dst[q] = make_float4(outv[4*q], outv[4*q+1], outv[4*q+2], outv[4*q+3]);
}

// ---------------------------------------------------------------------------
// Kernel 2: forward recurrence. wave = sentence, lane = tag j.
// Lane j holds column A'[.][j] = exp(WA)/64 (BOS col zeroed) in 64 VGPRs.
// Per step: 64 readlane-broadcasts of alpha + 64 fmac; constant 1/64 scaling
// folded into A' (logZ corrected by +255*log 64 at the end).
// ---------------------------------------------------------------------------
__global__ __launch_bounds__(256) void crf_forward_kernel(
    const int* __restrict__ words, const float* __restrict__ WA,
    const float* __restrict__ Bt, float* __restrict__ out)
{
    const int lane = threadIdx.x & 63;
    const int wv   = __builtin_amdgcn_readfirstlane((int)(threadIdx.x >> 6));
    const int b    = blockIdx.x * 4 + wv;        // 512 blocks * 4 waves = 2048

    // A' column for this lane: a_col[i] = exp(WA[i][lane]) * (lane==BOS?0:1/64)
    const float colmask = (lane == BOS_T) ? 0.f : 0.015625f;
    float a_col[64];
#pragma unroll
    for (int i = 0; i < 64; ++i)
        a_col[i] = expf(WA[i * 64 + lane]) * colmask;

    const int* wrow = words + (size_t)b * TLEN;

    float alpha = (lane == BOS_T) ? 1.f : 0.f;   // alpha_0 one-hot at BOS

    // 1-deep prefetch of the emission row
    float epre = Bt[(size_t)wrow[1] * KTAGS + lane];

    for (int t = 1; t <= 254; ++t) {
        float e = epre;
        if (t < 254)
            epre = Bt[(size_t)wrow[t + 1] * KTAGS + lane];

        float s0 = 0.f, s1 = 0.f, s2 = 0.f, s3 = 0.f;
        const int av = __float_as_int(alpha);
#pragma unroll
        for (int i = 0; i < 64; i += 4) {
            s0 = fmaf(__int_as_float(__builtin_amdgcn_readlane(av, i + 0)), a_col[i + 0], s0);
            s1 = fmaf(__int_as_float(__builtin_amdgcn_readlane(av, i + 1)), a_col[i + 1], s1);
            s2 = fmaf(__int_as_float(__builtin_amdgcn_readlane(av, i + 2)), a_col[i + 2], s2);
            s3 = fmaf(__int_as_float(__builtin_amdgcn_readlane(av, i + 3)), a_col[i + 3], s3);
        }
        alpha = ((s0 + s1) + (s2 + s3)) * e;
    }

    // final transition into EOS: p = sum_j alpha[j] * A'[j][EOS]
    const float aeos = expf(WA[lane * 64 + EOS_T]) * 0.015625f;
    float p = alpha * aeos;
#pragma unroll
    for (int off = 32; off >= 1; off >>= 1)
        p += __shfl_xor(p, off, 64);

    if (lane == 0)
        out[b] = logf(p) + 255.0f * 4.158883083359672f;  // + 255*log(64)
}

extern "C" void kernel_launch(void* const* d_in, const int* in_sizes, int n_in,
                              void* d_out, int out_size, void* d_ws, size_t ws_size,
                              hipStream_t stream) {
    const int*   words  = (const int*)d_in[0];
    const float* ThetaB = (const float*)d_in[1];
    const float* WA     = (const float*)d_in[2];
    const float* E      = (const float*)d_in[3];
    float*       outp   = (float*)d_out;
    float*       Bt     = (float*)d_ws;   // needs 50002*64*4 = 12.8 MB of ws

    // Kernel 1: 196 word-blocks x 2 tag-halves
    emis_table_kernel<<<dim3(392), dim3(256), 0, stream>>>(ThetaB, E, Bt);
    // Kernel 2: 512 blocks x 4 sentences/block
    crf_forward_kernel<<<dim3(512), dim3(256), 0, stream>>>(words, WA, Bt, outp);
}

// Round 2
// 225.910 us; speedup vs baseline: 1.0005x; 1.0005x over previous
//
#include <hip/hip_runtime.h>

// CRF forward logZ. Inputs (setup_inputs order):
//   d_in[0] words  int32 [2048][256]
//   d_in[1] ThetaB f32   [64][128]
//   d_in[2] WA     f32   [64][64]
//   d_in[3] E      f32   [50002][128]
// out: f32 [2048] logZ
// ws: Bt table [50002][64] f32 = 12.8 MB

#define VOCAB   50000
#define NROWS   50002   // V + 2
#define DDIM    128
#define KTAGS   64
#define EOS_T   62
#define BOS_T   63
#define BATCH   2048
#define TLEN    256
#define TINYV   1e-45f

// ---------------------------------------------------------------------------
// Kernel 1: Bt[w][k] = exp(sum_d ThetaB[k][d] * E[w][d]); rows k>=62 -> TINY.
// thread = word, 32 tags per thread (tag-half per block). ThetaB addresses are
// block-uniform -> scalar loads; E is per-lane sequential float4.
// __launch_bounds__(256,2): 256-VGPR cap so acc[32] stays in registers
// (R1: bare launch_bounds capped at 64 VGPR -> acc spilled -> ~105 us).
// ---------------------------------------------------------------------------
__global__ __launch_bounds__(256, 2) void emis_table_kernel(
    const float* __restrict__ ThetaB, const float* __restrict__ E,
    float* __restrict__ Bt)
{
    const int wblock = blockIdx.x >> 1;
    const int khalf  = blockIdx.x & 1;           // 0: tags 0..31, 1: tags 32..63
    const int w = wblock * 256 + threadIdx.x;
    if (w >= NROWS) return;

    const float4* E4 = (const float4*)E;         // row = 32 float4
    const float4* T4 = (const float4*)ThetaB;    // row = 32 float4

    float acc[32];
#pragma unroll
    for (int kk = 0; kk < 32; ++kk) acc[kk] = 0.f;

    for (int d4 = 0; d4 < 32; ++d4) {
        float4 e = E4[w * 32 + d4];
#pragma unroll
        for (int kk = 0; kk < 32; ++kk) {
            float4 tb = T4[(khalf * 32 + kk) * 32 + d4];   // block-uniform -> s_load
            acc[kk] = fmaf(e.x, tb.x, acc[kk]);
            acc[kk] = fmaf(e.y, tb.y, acc[kk]);
            acc[kk] = fmaf(e.z, tb.z, acc[kk]);
            acc[kk] = fmaf(e.w, tb.w, acc[kk]);
        }
    }

    float outv[32];
#pragma unroll
    for (int kk = 0; kk < 32; ++kk) outv[kk] = expf(acc[kk]);
    if (khalf) { outv[30] = TINYV; outv[31] = TINYV; }   // tags 62, 63

    float4* dst = (float4*)(Bt + (size_t)w * KTAGS + khalf * 32);
#pragma unroll
    for (int q = 0; q < 8; ++q)
        dst[q] = make_float4(outv[4*q], outv[4*q+1], outv[4*q+2], outv[4*q+3]);
}

// ---------------------------------------------------------------------------
// Kernel 2: forward recurrence. wave = sentence, lane = tag j.
// Lane j holds column A'[.][j] = exp(WA)/64 (BOS col zeroed) in 64 VGPRs.
// Per step: 64 readlane-broadcasts of alpha + 64 fmac; constant 1/64 scaling
// folded into A' (logZ corrected by +255*log 64 at the end).
// __launch_bounds__(256,2): R1 showed VGPR_Count=52 -> a_col[64] was spilled;
// this raises the cap to 256 so the column stays resident.
// ---------------------------------------------------------------------------
__global__ __launch_bounds__(256, 2) void crf_forward_kernel(
    const int* __restrict__ words, const float* __restrict__ WA,
    const float* __restrict__ Bt, float* __restrict__ out)
{
    const int lane = threadIdx.x & 63;
    const int wv   = __builtin_amdgcn_readfirstlane((int)(threadIdx.x >> 6));
    const int b    = blockIdx.x * 4 + wv;        // 512 blocks * 4 waves = 2048

    // A' column for this lane: a_col[i] = exp(WA[i][lane]) * (lane==BOS?0:1/64)
    const float colmask = (lane == BOS_T) ? 0.f : 0.015625f;
    float a_col[64];
#pragma unroll
    for (int i = 0; i < 64; ++i)
        a_col[i] = expf(WA[i * 64 + lane]) * colmask;

    const int* wrow = words + (size_t)b * TLEN;

    float alpha = (lane == BOS_T) ? 1.f : 0.f;   // alpha_0 one-hot at BOS

    // 1-deep prefetch of the emission row
    float epre = Bt[(size_t)wrow[1] * KTAGS + lane];

    for (int t = 1; t <= 254; ++t) {
        float e = epre;
        if (t < 254)
            epre = Bt[(size_t)wrow[t + 1] * KTAGS + lane];

        float s0 = 0.f, s1 = 0.f, s2 = 0.f, s3 = 0.f;
        const int av = __float_as_int(alpha);
#pragma unroll
        for (int i = 0; i < 64; i += 4) {
            s0 = fmaf(__int_as_float(__builtin_amdgcn_readlane(av, i + 0)), a_col[i + 0], s0);
            s1 = fmaf(__int_as_float(__builtin_amdgcn_readlane(av, i + 1)), a_col[i + 1], s1);
            s2 = fmaf(__int_as_float(__builtin_amdgcn_readlane(av, i + 2)), a_col[i + 2], s2);
            s3 = fmaf(__int_as_float(__builtin_amdgcn_readlane(av, i + 3)), a_col[i + 3], s3);
        }
        alpha = ((s0 + s1) + (s2 + s3)) * e;
    }

    // final transition into EOS: p = sum_j alpha[j] * A'[j][EOS]
    const float aeos = expf(WA[lane * 64 + EOS_T]) * 0.015625f;
    float p = alpha * aeos;
#pragma unroll
    for (int off = 32; off >= 1; off >>= 1)
        p += __shfl_xor(p, off, 64);

    if (lane == 0)
        out[b] = logf(p) + 255.0f * 4.158883083359672f;  // + 255*log(64)
}

extern "C" void kernel_launch(void* const* d_in, const int* in_sizes, int n_in,
                              void* d_out, int out_size, void* d_ws, size_t ws_size,
                              hipStream_t stream) {
    const int*   words  = (const int*)d_in[0];
    const float* ThetaB = (const float*)d_in[1];
    const float* WA     = (const float*)d_in[2];
    const float* E      = (const float*)d_in[3];
    float*       outp   = (float*)d_out;
    float*       Bt     = (float*)d_ws;   // needs 50002*64*4 = 12.8 MB of ws

    // Kernel 1: 196 word-blocks x 2 tag-halves
    emis_table_kernel<<<dim3(392), dim3(256), 0, stream>>>(ThetaB, E, Bt);
    // Kernel 2: 512 blocks x 4 sentences/block
    crf_forward_kernel<<<dim3(512), dim3(256), 0, stream>>>(words, WA, Bt, outp);
}